// Round 3
// baseline (131.362 us; speedup 1.0000x reference)
//
#include <hip/hip_runtime.h>

#define NN 32      // nodes
#define DSA 64     // node feature dim
#define DH 128     // hidden dim

#define LDX 68     // LDS stride (floats) for xs rows (272 B -> bank step 4, conflict-free)
#define LDC 36     // LDS stride for W chunk rows     (144 B -> bank step 4, conflict-free)
#define LDA 132    // LDS stride for value buffers    (528 B -> bank step 4, conflict-free)
#define THREADS 256

__device__ __forceinline__ float relu_(float v) { return fmaxf(v, 0.f); }

// ---- per-wave W staging: wave w owns Ws rows [32w, 32w+32), 32 cols per chunk ----
// lane l covers (row = l/8, col4 = l%8) + 3 more rows at +8 stride: 4 float4/lane.

__device__ __forceinline__ void load_pf(const float* __restrict__ W, int w_ld,
                                        int row0, int c0, int lane, float4 pf[4]) {
  #pragma unroll
  for (int r4 = 0; r4 < 4; ++r4) {
    int f = lane + (r4 << 6);          // 0..255
    int row = f >> 3;                  // 0..31
    int c4 = (f & 7) << 2;
    pf[r4] = *(const float4*)(W + (row0 + row) * w_ld + c0 + c4);
  }
}

__device__ __forceinline__ void write_pf(float* __restrict__ WsWave, int lane,
                                         const float4 pf[4]) {
  #pragma unroll
  for (int r4 = 0; r4 < 4; ++r4) {
    int f = lane + (r4 << 6);
    int row = f >> 3;
    int c4 = (f & 7) << 2;
    *(float4*)(WsWave + row * LDC + c4) = pf[r4];
  }
}

// acc[m][k] += sum_{d<32} In[8m rows][d] * Wch[8k rows][d]; operands pre-offset.
template<int LDI>
__device__ __forceinline__ void chunk_mac(const float* __restrict__ In,
                                          const float* __restrict__ Wb,
                                          float acc[4][4]) {
  #pragma unroll
  for (int d = 0; d < 32; d += 4) {
    float4 xv[4], wv[4];
    #pragma unroll
    for (int m = 0; m < 4; ++m) xv[m] = *(const float4*)(In + m * 8 * LDI + d);
    #pragma unroll
    for (int k = 0; k < 4; ++k) wv[k] = *(const float4*)(Wb + k * 8 * LDC + d);
    #pragma unroll
    for (int m = 0; m < 4; ++m)
      #pragma unroll
      for (int k = 0; k < 4; ++k) {
        acc[m][k] = fmaf(xv[m].x, wv[k].x, acc[m][k]);
        acc[m][k] = fmaf(xv[m].y, wv[k].y, acc[m][k]);
        acc[m][k] = fmaf(xv[m].z, wv[k].z, acc[m][k]);
        acc[m][k] = fmaf(xv[m].w, wv[k].w, acc[m][k]);
      }
  }
}

// Per-wave GEMM over NCH 32-col K-chunks. NO block barriers: wave-private Ws
// region, same-wave DS ordering + lgkmcnt drain. Register double-buffer pfA/pfB
// overlaps chunk c+1 global loads with chunk c FMAs.
template<int NCH, int LDI>
__device__ __forceinline__ void gemm_pw(const float* __restrict__ W, int w_ld, int wc0,
                                        const float* __restrict__ InBase,
                                        float* __restrict__ WsWave,
                                        const float* __restrict__ wB,
                                        int lane, int wrow0, float acc[4][4]) {
  float4 pfA[4], pfB[4];
  load_pf(W, w_ld, wrow0, wc0, lane, pfA);
  #pragma unroll
  for (int c = 0; c < NCH; ++c) {
    if (c & 1) {
      write_pf(WsWave, lane, pfB);
      if (c + 1 < NCH) load_pf(W, w_ld, wrow0, wc0 + 32 * (c + 1), lane, pfA);
    } else {
      write_pf(WsWave, lane, pfA);
      if (c + 1 < NCH) load_pf(W, w_ld, wrow0, wc0 + 32 * (c + 1), lane, pfB);
    }
    // Drain ds_writes so same-wave cross-lane reads see them; "memory" stops
    // the compiler moving chunk_mac's ds_reads above. (Next chunk's global
    // loads were issued BEFORE this point -> they overlap the FMAs below.)
    asm volatile("s_waitcnt lgkmcnt(0)" ::: "memory");
    chunk_mac<LDI>(InBase + 32 * c, wB, acc);
  }
}

__device__ __forceinline__ void zero_acc(float acc[4][4]) {
  #pragma unroll
  for (int m = 0; m < 4; ++m)
    #pragma unroll
    for (int k = 0; k < 4; ++k) acc[m][k] = 0.f;
}

// mode: 0 = raw, 1 = +bias, 2 = relu(+bias)
template<int MODE>
__device__ __forceinline__ void store_tile(float* __restrict__ Bf, int igrp, int hbase,
                                           const float acc[4][4],
                                           const float* __restrict__ bias) {
  #pragma unroll
  for (int k = 0; k < 4; ++k) {
    float bk = (MODE > 0) ? bias[hbase + 8 * k] : 0.f;
    #pragma unroll
    for (int m = 0; m < 4; ++m) {
      float v = acc[m][k] + bk;
      if (MODE == 2) v = relu_(v);
      Bf[(igrp + 8 * m) * LDA + hbase + 8 * k] = v;
    }
  }
}

// G[i][h] = sum_{j != i} relu(A[j][h] + C[i][h]); bias pre-folded into C.
// Fully wave-local: columns hbase+8k lie in wave w's quarter, written by wave w.
__device__ __forceinline__ void aggregate(const float* __restrict__ Ab,
                                          const float* __restrict__ Cb,
                                          float* __restrict__ Gb,
                                          int igrp, int hbase) {
  asm volatile("s_waitcnt lgkmcnt(0)" ::: "memory");   // own-wave stores visible
  float cv[4][4], sg[4][4];
  #pragma unroll
  for (int m = 0; m < 4; ++m)
    #pragma unroll
    for (int k = 0; k < 4; ++k) {
      cv[m][k] = Cb[(igrp + 8 * m) * LDA + hbase + 8 * k];
      sg[m][k] = 0.f;
    }
  #pragma unroll 4
  for (int j = 0; j < NN; ++j) {
    float av[4];
    #pragma unroll
    for (int k = 0; k < 4; ++k) av[k] = Ab[j * LDA + hbase + 8 * k];
    #pragma unroll
    for (int m = 0; m < 4; ++m)
      #pragma unroll
      for (int k = 0; k < 4; ++k)
        sg[m][k] += relu_(av[k] + cv[m][k]);
  }
  #pragma unroll
  for (int m = 0; m < 4; ++m) {
    const int i = igrp + 8 * m;
    #pragma unroll
    for (int k = 0; k < 4; ++k) {
      float self = relu_(Ab[i * LDA + hbase + 8 * k] + cv[m][k]);
      Gb[i * LDA + hbase + 8 * k] = sg[m][k] - self;
    }
  }
  asm volatile("s_waitcnt lgkmcnt(0)" ::: "memory");   // G visible to own wave
}

// LDS: xs 8704 + Ws 18432 + 3*16896 + red = ~78.1 KB -> 2 blocks/CU (8 waves/CU)
__global__ __launch_bounds__(THREADS, 2)
void mgn_fused(const float* __restrict__ x,
               const float* __restrict__ Wm1, const float* __restrict__ bm1,
               const float* __restrict__ Wm2, const float* __restrict__ bm2,
               const float* __restrict__ Wu1, const float* __restrict__ bu1,
               const float* __restrict__ Wu2, const float* __restrict__ bu2,
               const float* __restrict__ Wv,  const float* __restrict__ bv,
               float* __restrict__ out) {
  __shared__ __align__(16) float xs[NN * LDX];
  __shared__ __align__(16) float Ws[DH * LDC];
  __shared__ __align__(16) float Pb[NN * LDA];
  __shared__ __align__(16) float Qb[NN * LDA];
  __shared__ __align__(16) float Rb[NN * LDA];
  __shared__ float red[2];

  const int t = threadIdx.x;
  const int b = blockIdx.x;
  const int w = t >> 6;            // wave 0..3
  const int lane = t & 63;
  const int hsub = (t >> 3) & 7;
  const int igrp = t & 7;
  const int wrow0 = w << 5;        // wave's W-row / value-column quarter origin
  const int hbase = wrow0 + hsub;  // thread cols: hbase + 8k ; thread rows: igrp + 8m

  const float* inX = xs + igrp * LDX;
  const float* inP = Pb + igrp * LDA;
  const float* inR = Rb + igrp * LDA;
  float* WsW = Ws + wrow0 * LDC;         // wave-private staging region
  const float* wB = Ws + hbase * LDC;

  float acc[4][4];

  // ---- load x_b (2048 floats, 512 float4, block-coalesced) ----
  {
    const float* xb = x + b * (NN * DSA);
    #pragma unroll
    for (int r = 0; r < 2; ++r) {
      int f = t + (r << 8);
      int row = f >> 4;
      int c4 = (f & 15) << 2;
      float4 v = *(const float4*)(xb + (f << 2));
      *(float4*)(xs + row * LDX + c4) = v;
    }
  }
  __syncthreads();                                   // B1: xs ready for all waves

  // ---- A1 = x @ Wm1[:, 0:64].T -> P  (wave-local from here to v1-part-x) ----
  zero_acc(acc);
  gemm_pw<2, LDX>(Wm1, 2 * DSA, 0, inX, WsW, wB, lane, wrow0, acc);
  store_tile<0>(Pb, igrp, hbase, acc, nullptr);

  // ---- C1 = x @ Wm1[:, 64:128].T + bm1 -> Q ----
  zero_acc(acc);
  gemm_pw<2, LDX>(Wm1, 2 * DSA, DSA, inX, WsW, wB, lane, wrow0, acc);
  store_tile<1>(Qb, igrp, hbase, acc, bm1);

  // ---- agg1(P,Q) -> R  (wave-local) ----
  aggregate(Pb, Qb, Rb, igrp, hbase);

  // ---- v1 = relu(x @ Wu1x.T + agg1 @ Wu1g.T + bu1) -> P ----
  zero_acc(acc);
  gemm_pw<2, LDX>(Wu1, DH + DSA, 0, inX, WsW, wB, lane, wrow0, acc);
  __syncthreads();                                   // B2: R complete (g-GEMM reads all cols)
  gemm_pw<4, LDA>(Wu1, DH + DSA, DSA, inR, WsW, wB, lane, wrow0, acc);
  store_tile<2>(Pb, igrp, hbase, acc, bu1);
  __syncthreads();                                   // B3: v1(P) complete before K-dim reads

  // ---- A2 = v1 @ Wm2[:, 0:128].T -> Q ----
  zero_acc(acc);
  gemm_pw<4, LDA>(Wm2, 2 * DH, 0, inP, WsW, wB, lane, wrow0, acc);
  store_tile<0>(Qb, igrp, hbase, acc, nullptr);

  // ---- C2 = v1 @ Wm2[:, 128:256].T + bm2 -> R ----
  zero_acc(acc);
  gemm_pw<4, LDA>(Wm2, 2 * DH, DH, inP, WsW, wB, lane, wrow0, acc);
  store_tile<1>(Rb, igrp, hbase, acc, bm2);
  __syncthreads();                                   // B4: all waves done reading P (WAR before agg2 writes P)

  // ---- agg2(Q,R) -> P  (wave-local) ----
  aggregate(Qb, Rb, Pb, igrp, hbase);

  // ---- v2 = relu(x @ Wu2x.T + agg2 @ Wu2g.T + bu2) -> Q ----
  zero_acc(acc);
  gemm_pw<2, LDX>(Wu2, DH + DSA, 0, inX, WsW, wB, lane, wrow0, acc);
  __syncthreads();                                   // B5: agg2(P) complete (g-GEMM reads all cols; Q dead everywhere)
  gemm_pw<4, LDA>(Wu2, DH + DSA, DSA, inP, WsW, wB, lane, wrow0, acc);
  store_tile<2>(Qb, igrp, hbase, acc, bu2);
  __syncthreads();                                   // B6: v2 complete before cross-wave column max

  // ---- out[b] = sum_h Wv[h] * max_i v2[i][h] + bv ----
  if (t < DH) {
    const float* q = Qb + t;
    float mx = q[0];
    #pragma unroll
    for (int i = 1; i < NN; ++i) mx = fmaxf(mx, q[i * LDA]);
    float partial = mx * Wv[t];
    #pragma unroll
    for (int off = 32; off; off >>= 1) partial += __shfl_down(partial, off, 64);
    if (lane == 0) red[w] = partial;
  }
  __syncthreads();                                   // B7
  if (t == 0) out[b] = red[0] + red[1] + bv[0];
}

extern "C" void kernel_launch(void* const* d_in, const int* in_sizes, int n_in,
                              void* d_out, int out_size, void* d_ws, size_t ws_size,
                              hipStream_t stream) {
  (void)n_in; (void)out_size; (void)d_ws; (void)ws_size;
  const float* x   = (const float*)d_in[0];
  // d_in[1] = ext_adj: all-pairs-minus-self structure, folded analytically.
  const float* Wm1 = (const float*)d_in[2];
  const float* bm1 = (const float*)d_in[3];
  const float* Wm2 = (const float*)d_in[4];
  const float* bm2 = (const float*)d_in[5];
  const float* Wu1 = (const float*)d_in[6];
  const float* bu1 = (const float*)d_in[7];
  const float* Wu2 = (const float*)d_in[8];
  const float* bu2 = (const float*)d_in[9];
  const float* Wv  = (const float*)d_in[10];
  const float* bv  = (const float*)d_in[11];
  float* out = (float*)d_out;

  const int B = in_sizes[0] / (NN * DSA);   // 512
  mgn_fused<<<dim3(B), dim3(THREADS), 0, stream>>>(
      x, Wm1, bm1, Wm2, bm2, Wu1, bu1, Wu2, bu2, Wv, bv, out);
}

// Round 8
// 106.688 us; speedup vs baseline: 1.2313x; 1.2313x over previous
//
#include <hip/hip_runtime.h>

#define NN 32
#define DSA 64
#define DH 128
#define LDPQ 132          // f32 LDS stride for P/Q (528B -> conflict-benign scalar access)
#define THREADS 256

typedef float f32x4 __attribute__((ext_vector_type(4)));
typedef short short8 __attribute__((ext_vector_type(8)));
typedef __bf16 bfrag __attribute__((ext_vector_type(8)));
typedef unsigned short us4 __attribute__((ext_vector_type(4)));

#define MFMA_(a, b, c) __builtin_amdgcn_mfma_f32_16x16x32_bf16((a), (b), (c), 0, 0, 0)

__device__ __forceinline__ float relu_(float v) { return fmaxf(v, 0.f); }

// f32 -> (hi = truncated bf16, lo = RNE bf16 of residual); a ≈ hi+lo to ~2^-17 rel.
__device__ __forceinline__ void split2(float f, unsigned short& h, unsigned short& l) {
  unsigned u = __float_as_uint(f);
  h = (unsigned short)(u >> 16);
  float lo = f - __uint_as_float(u & 0xffff0000u);
  unsigned v = __float_as_uint(lo);
  l = (unsigned short)((v + 0x7fffu + ((v >> 16) & 1u)) >> 16);
}

// 8 f32 (two float4) -> hi/lo bf16 fragments
__device__ __forceinline__ void cvt8(const float4 a, const float4 b, bfrag& bh, bfrag& bl) {
  float f[8] = {a.x, a.y, a.z, a.w, b.x, b.y, b.z, b.w};
  short8 h, l;
  #pragma unroll
  for (int j = 0; j < 8; ++j) {
    unsigned short hh, ll;
    split2(f[j], hh, ll);
    h[j] = (short)hh;
    l[j] = (short)ll;
  }
  bh = __builtin_bit_cast(bfrag, h);
  bl = __builtin_bit_cast(bfrag, l);
}

// One GEMM part: acc[m][n] += In(32 x 32*NK) . W[:, c0:c0+32*NK]^T for the wave's
// 32 h-columns (2 N-tiles). A from swizzled split-bf16 LDS (row stride RS ushorts),
// B from pre-split global (PRE) or f32 global + inline split (!PRE).
template<int NK, int RS, bool PRE>
__device__ __forceinline__ void mfma_part(const unsigned short* __restrict__ Ah,
                                          const unsigned short* __restrict__ Al,
                                          const float* __restrict__ W, int ld, int c0,
                                          const unsigned short* __restrict__ Bh,
                                          const unsigned short* __restrict__ Bl,
                                          int lane, int w, f32x4 acc[2][2]) {
  const int g = lane >> 4;        // k-octet 0..3
  const int c = lane & 15;        // M-row / N-col within tile
  const int swz = (c & 7) << 3;
  #pragma unroll
  for (int kt = 0; kt < NK; ++kt) {
    const int o = c0 + kt * 32 + g * 8;
    bfrag b0h, b0l, b1h, b1l;
    if constexpr (PRE) {
      const int rowA = (32 * w + c) * ld + o;
      const int rowB = (32 * w + 16 + c) * ld + o;
      b0h = *(const bfrag*)(Bh + rowA);
      b0l = *(const bfrag*)(Bl + rowA);
      b1h = *(const bfrag*)(Bh + rowB);
      b1l = *(const bfrag*)(Bl + rowB);
    } else {
      const float* wp0 = W + (32 * w + c) * ld + o;
      const float* wp1 = wp0 + 16 * ld;
      cvt8(*(const float4*)wp0, *(const float4*)(wp0 + 4), b0h, b0l);
      cvt8(*(const float4*)wp1, *(const float4*)(wp1 + 4), b1h, b1l);
    }
    const int i0 = ((c) * RS + kt * 32 + g * 8) ^ swz;
    const int i1 = ((16 + c) * RS + kt * 32 + g * 8) ^ swz;  // (16+c)&7 == c&7
    bfrag a0h = *(const bfrag*)(Ah + i0);
    bfrag a0l = *(const bfrag*)(Al + i0);
    bfrag a1h = *(const bfrag*)(Ah + i1);
    bfrag a1l = *(const bfrag*)(Al + i1);
    acc[0][0] = MFMA_(a0h, b0h, acc[0][0]);
    acc[0][1] = MFMA_(a0h, b1h, acc[0][1]);
    acc[1][0] = MFMA_(a1h, b0h, acc[1][0]);
    acc[1][1] = MFMA_(a1h, b1h, acc[1][1]);
    acc[0][0] = MFMA_(a0h, b0l, acc[0][0]);
    acc[0][1] = MFMA_(a0h, b1l, acc[0][1]);
    acc[1][0] = MFMA_(a1h, b0l, acc[1][0]);
    acc[1][1] = MFMA_(a1h, b1l, acc[1][1]);
    acc[0][0] = MFMA_(a0l, b0h, acc[0][0]);
    acc[0][1] = MFMA_(a0l, b1h, acc[0][1]);
    acc[1][0] = MFMA_(a1l, b0h, acc[1][0]);
    acc[1][1] = MFMA_(a1l, b1h, acc[1][1]);
    acc[0][0] = MFMA_(a0l, b0l, acc[0][0]);
    acc[0][1] = MFMA_(a0l, b1l, acc[0][1]);
    acc[1][0] = MFMA_(a1l, b0l, acc[1][0]);
    acc[1][1] = MFMA_(a1l, b1l, acc[1][1]);
  }
}

__device__ __forceinline__ void zero_acc(f32x4 acc[2][2]) {
  f32x4 z = {0.f, 0.f, 0.f, 0.f};
  acc[0][0] = z; acc[0][1] = z; acc[1][0] = z; acc[1][1] = z;
}

// D-frag (col = lane&15, row = (lane>>4)*4+reg) -> f32 LDS [row][col]
template<bool BIAS>
__device__ __forceinline__ void store_pq(float* __restrict__ Bf, const f32x4 acc[2][2],
                                         int lane, int w, float bn0, float bn1) {
  const int g = lane >> 4, c = lane & 15;
  #pragma unroll
  for (int mt = 0; mt < 2; ++mt)
    #pragma unroll
    for (int n = 0; n < 2; ++n) {
      const float bb = BIAS ? (n ? bn1 : bn0) : 0.f;
      #pragma unroll
      for (int r = 0; r < 4; ++r) {
        const int row = mt * 16 + g * 4 + r;
        const int col = 32 * w + 16 * n + c;
        Bf[row * LDPQ + col] = acc[mt][n][r] + bb;
      }
    }
}

// relu(acc + bias) -> swizzled split-bf16 LDS (row stride 128)
__device__ __forceinline__ void store_v(unsigned short* __restrict__ Gh,
                                        unsigned short* __restrict__ Gl,
                                        const f32x4 acc[2][2], int lane, int w,
                                        float bn0, float bn1) {
  const int g = lane >> 4, c = lane & 15;
  #pragma unroll
  for (int mt = 0; mt < 2; ++mt)
    #pragma unroll
    for (int n = 0; n < 2; ++n) {
      const float bb = n ? bn1 : bn0;
      #pragma unroll
      for (int r = 0; r < 4; ++r) {
        const int row = mt * 16 + g * 4 + r;
        const int col = 32 * w + 16 * n + c;
        const float v = relu_(acc[mt][n][r] + bb);
        unsigned short hh, ll;
        split2(v, hh, ll);
        const int idx = (row * DH + col) ^ ((row & 7) << 3);
        Gh[idx] = hh;
        Gl[idx] = ll;
      }
    }
}

// G[i][h] = sum_{j!=i} relu(A[j][h] + C[i][h]) -> swizzled split-bf16. Wave-local cols.
__device__ __forceinline__ void aggregate(const float* __restrict__ Ab,
                                          const float* __restrict__ Cb,
                                          unsigned short* __restrict__ Gh,
                                          unsigned short* __restrict__ Gl,
                                          int igrp, int hbase) {
  asm volatile("s_waitcnt lgkmcnt(0)" ::: "memory");   // own-wave P/Q writes visible
  float cv[4][4], sg[4][4];
  #pragma unroll
  for (int m = 0; m < 4; ++m)
    #pragma unroll
    for (int k = 0; k < 4; ++k) {
      cv[m][k] = Cb[(igrp + 8 * m) * LDPQ + hbase + 8 * k];
      sg[m][k] = 0.f;
    }
  #pragma unroll 4
  for (int j = 0; j < NN; ++j) {
    float av[4];
    #pragma unroll
    for (int k = 0; k < 4; ++k) av[k] = Ab[j * LDPQ + hbase + 8 * k];
    #pragma unroll
    for (int m = 0; m < 4; ++m)
      #pragma unroll
      for (int k = 0; k < 4; ++k)
        sg[m][k] += relu_(av[k] + cv[m][k]);
  }
  #pragma unroll
  for (int m = 0; m < 4; ++m) {
    const int i = igrp + 8 * m;
    #pragma unroll
    for (int k = 0; k < 4; ++k) {
      const int h = hbase + 8 * k;
      const float self = relu_(Ab[i * LDPQ + h] + cv[m][k]);
      const float val = sg[m][k] - self;
      unsigned short hh, ll;
      split2(val, hh, ll);
      const int idx = (i * DH + h) ^ ((i & 7) << 3);
      Gh[idx] = hh;
      Gl[idx] = ll;
    }
  }
}

// Pre-split all weights f32 -> (hi, lo) bf16 into d_ws. 24576 float4 total.
__global__ void preconv(const float* __restrict__ Wm1, const float* __restrict__ Wu1,
                        const float* __restrict__ Wm2, const float* __restrict__ Wu2,
                        unsigned short* __restrict__ ws) {
  const int tid = blockIdx.x * blockDim.x + threadIdx.x;
  const float* src; unsigned short *dh, *dl; int loc;
  if (tid < 4096)        { src = Wm1; dh = ws;          dl = ws + 16384;  loc = tid; }
  else if (tid < 10240)  { src = Wu1; dh = ws + 32768;  dl = ws + 57344;  loc = tid - 4096; }
  else if (tid < 18432)  { src = Wm2; dh = ws + 81920;  dl = ws + 114688; loc = tid - 10240; }
  else                   { src = Wu2; dh = ws + 147456; dl = ws + 172032; loc = tid - 18432; }
  float4 v = *(const float4*)(src + loc * 4);
  float f[4] = {v.x, v.y, v.z, v.w};
  us4 h, l;
  #pragma unroll
  for (int j = 0; j < 4; ++j) {
    unsigned short hh, ll;
    split2(f[j], hh, ll);
    h[j] = hh;
    l[j] = ll;
  }
  *(us4*)(dh + loc * 4) = h;
  *(us4*)(dl + loc * 4) = l;
}

// LDS: P,Q f32 (2*16896) + X split (8192B) + R,V split (32768B) + red ≈ 74.8 KB -> 2 blk/CU
template<bool PRE>
__global__ __launch_bounds__(THREADS, 2)
void mgn_mfma(const float* __restrict__ x,
              const float* __restrict__ Wm1, const float* __restrict__ bm1,
              const float* __restrict__ Wm2, const float* __restrict__ bm2,
              const float* __restrict__ Wu1, const float* __restrict__ bu1,
              const float* __restrict__ Wu2, const float* __restrict__ bu2,
              const float* __restrict__ Wv,  const float* __restrict__ bv,
              const unsigned short* __restrict__ wsplit,
              float* __restrict__ out) {
  __shared__ __align__(16) float Pb[NN * LDPQ];
  __shared__ __align__(16) float Qb[NN * LDPQ];
  __shared__ __align__(16) unsigned short Xh[NN * DSA], Xl[NN * DSA];
  __shared__ __align__(16) unsigned short Rh[NN * DH],  Rl[NN * DH];
  __shared__ __align__(16) unsigned short Vh[NN * DH],  Vl[NN * DH];
  __shared__ float red[4];

  const int t = threadIdx.x;
  const int b = blockIdx.x;
  const int w = t >> 6;
  const int lane = t & 63;
  const int c = lane & 15;
  const int hsub = (t >> 3) & 7;
  const int igrp = t & 7;
  const int hbase = (w << 5) + hsub;

  // pre-split W segment pointers (PRE path)
  const unsigned short *m1h = wsplit,           *m1l = wsplit + 16384;
  const unsigned short *u1h = wsplit + 32768,   *u1l = wsplit + 57344;
  const unsigned short *m2h = wsplit + 81920,   *m2l = wsplit + 114688;
  const unsigned short *u2h = wsplit + 147456,  *u2l = wsplit + 172032;

  // per-lane bias / Wv preloads (col h = 32w + 16n + c)
  const int h0 = 32 * w + c, h1 = h0 + 16;
  const float bm1_0 = bm1[h0], bm1_1 = bm1[h1];
  const float bu1_0 = bu1[h0], bu1_1 = bu1[h1];
  const float bm2_0 = bm2[h0], bm2_1 = bm2[h1];
  const float bu2_0 = bu2[h0], bu2_1 = bu2[h1];
  const float wv0 = Wv[h0], wv1 = Wv[h1];

  // ---- stage x_b as swizzled split-bf16 ----
  {
    const float* xb = x + b * (NN * DSA);
    #pragma unroll
    for (int r = 0; r < 2; ++r) {
      const int f = t + (r << 8);            // float4 id 0..511
      const int row = f >> 4;
      const int c0 = (f & 15) << 2;
      float4 v = *(const float4*)(xb + (f << 2));
      float fv[4] = {v.x, v.y, v.z, v.w};
      us4 hh, ll;
      #pragma unroll
      for (int j = 0; j < 4; ++j) {
        unsigned short a_, b_;
        split2(fv[j], a_, b_);
        hh[j] = a_;
        ll[j] = b_;
      }
      const int idx = ((row << 6) + c0) ^ ((row & 7) << 3);
      *(us4*)(Xh + idx) = hh;
      *(us4*)(Xl + idx) = ll;
    }
  }
  __syncthreads();                                        // B1: X staged

  f32x4 acc[2][2];

  // ---- A1 = x @ Wm1[:, 0:64]^T -> P ----
  zero_acc(acc);
  mfma_part<2, DSA, PRE>(Xh, Xl, Wm1, 2 * DSA, 0,   m1h, m1l, lane, w, acc);
  store_pq<false>(Pb, acc, lane, w, 0.f, 0.f);

  // ---- C1 = x @ Wm1[:, 64:128]^T + bm1 -> Q ----
  zero_acc(acc);
  mfma_part<2, DSA, PRE>(Xh, Xl, Wm1, 2 * DSA, DSA, m1h, m1l, lane, w, acc);
  store_pq<true>(Qb, acc, lane, w, bm1_0, bm1_1);

  // ---- agg1(P,Q) -> R (wave-local) ----
  aggregate(Pb, Qb, Rh, Rl, igrp, hbase);

  // ---- v1 = relu(x @ Wu1x^T + agg1 @ Wu1g^T + bu1) -> V ----
  zero_acc(acc);
  mfma_part<2, DSA, PRE>(Xh, Xl, Wu1, DH + DSA, 0, u1h, u1l, lane, w, acc);
  __syncthreads();                                        // B2: all R writes done
  mfma_part<4, DH, PRE>(Rh, Rl, Wu1, DH + DSA, DSA, u1h, u1l, lane, w, acc);
  store_v(Vh, Vl, acc, lane, w, bu1_0, bu1_1);
  __syncthreads();                                        // B3: V complete

  // ---- A2 = v1 @ Wm2[:, 0:128]^T -> P ----
  zero_acc(acc);
  mfma_part<4, DH, PRE>(Vh, Vl, Wm2, 2 * DH, 0,  m2h, m2l, lane, w, acc);
  store_pq<false>(Pb, acc, lane, w, 0.f, 0.f);

  // ---- C2 = v1 @ Wm2[:, 128:256]^T + bm2 -> Q ----
  zero_acc(acc);
  mfma_part<4, DH, PRE>(Vh, Vl, Wm2, 2 * DH, DH, m2h, m2l, lane, w, acc);
  store_pq<true>(Qb, acc, lane, w, bm2_0, bm2_1);

  // ---- agg2(P,Q) -> R (wave-local; prior R readers all pre-B3) ----
  aggregate(Pb, Qb, Rh, Rl, igrp, hbase);

  // ---- v2 = relu(x @ Wu2x^T + agg2 @ Wu2g^T + bu2), stays in regs ----
  zero_acc(acc);
  mfma_part<2, DSA, PRE>(Xh, Xl, Wu2, DH + DSA, 0, u2h, u2l, lane, w, acc);
  __syncthreads();                                        // B4: all R2 writes done
  mfma_part<4, DH, PRE>(Rh, Rl, Wu2, DH + DSA, DSA, u2h, u2l, lane, w, acc);

  // ---- out[b] = sum_h Wv[h] * max_i relu(v2[i][h]) + bv ----
  float cm0 = 0.f, cm1 = 0.f;                             // relu >= 0 so init 0 is exact
  #pragma unroll
  for (int mt = 0; mt < 2; ++mt)
    #pragma unroll
    for (int r = 0; r < 4; ++r) {
      cm0 = fmaxf(cm0, acc[mt][0][r] + bu2_0);
      cm1 = fmaxf(cm1, acc[mt][1][r] + bu2_1);
    }
  cm0 = fmaxf(cm0, __shfl_xor(cm0, 16));
  cm0 = fmaxf(cm0, __shfl_xor(cm0, 32));
  cm1 = fmaxf(cm1, __shfl_xor(cm1, 16));
  cm1 = fmaxf(cm1, __shfl_xor(cm1, 32));
  float part = cm0 * wv0 + cm1 * wv1;
  if (lane >= 16) part = 0.f;                              // count each column once
  #pragma unroll
  for (int off = 32; off >= 1; off >>= 1) part += __shfl_xor(part, off);
  if (lane == 0) red[w] = part;
  __syncthreads();                                        // B5
  if (t == 0) out[b] = red[0] + red[1] + red[2] + red[3] + bv[0];
}

extern "C" void kernel_launch(void* const* d_in, const int* in_sizes, int n_in,
                              void* d_out, int out_size, void* d_ws, size_t ws_size,
                              hipStream_t stream) {
  (void)n_in; (void)out_size;
  const float* x   = (const float*)d_in[0];
  // d_in[1] = ext_adj: all-pairs-minus-self structure, folded analytically.
  const float* Wm1 = (const float*)d_in[2];
  const float* bm1 = (const float*)d_in[3];
  const float* Wm2 = (const float*)d_in[4];
  const float* bm2 = (const float*)d_in[5];
  const float* Wu1 = (const float*)d_in[6];
  const float* bu1 = (const float*)d_in[7];
  const float* Wu2 = (const float*)d_in[8];
  const float* bu2 = (const float*)d_in[9];
  const float* Wv  = (const float*)d_in[10];
  const float* bv  = (const float*)d_in[11];
  float* out = (float*)d_out;

  const int B = in_sizes[0] / (NN * DSA);   // 512
  const bool pre = ws_size >= 196608u * sizeof(unsigned short);
  if (pre) {
    unsigned short* ws = (unsigned short*)d_ws;
    preconv<<<dim3(96), dim3(THREADS), 0, stream>>>(Wm1, Wu1, Wm2, Wu2, ws);
    mgn_mfma<true><<<dim3(B), dim3(THREADS), 0, stream>>>(
        x, Wm1, bm1, Wm2, bm2, Wu1, bu1, Wu2, bu2, Wv, bv, ws, out);
  } else {
    mgn_mfma<false><<<dim3(B), dim3(THREADS), 0, stream>>>(
        x, Wm1, bm1, Wm2, bm2, Wu1, bu1, Wu2, bu2, Wv, bv, nullptr, out);
  }
}